// Round 7
// baseline (911.958 us; speedup 1.0000x reference)
//
#include <hip/hip_runtime.h>

#define N_NODES 100000
#define N_EDGES 1600000
#define IN_F 128
#define OUT_F 64
#define ALPHA 10.0f
#define SCAN_T 1024
#define CHUNK ((N_NODES + SCAN_T - 1) / SCAN_T)   // 98 nodes per scan thread

// ---------------- K1: float degree + int histogram ----------------
__global__ void deg_hist_kernel(const int* __restrict__ dst, const int* __restrict__ ef,
                                const float* __restrict__ edge_weight,
                                float* __restrict__ deg, int* __restrict__ cnt, int E) {
    int e = blockIdx.x * blockDim.x + threadIdx.x;
    if (e < E) {
        float w = edge_weight[ef[e] - 1] * ALPHA;
        float ew = w > 0.0f ? w : 0.01f * w;   // leaky_relu, slope 0.01
        int d = dst[e];
        atomicAdd(&deg[d], ew);
        atomicAdd(&cnt[d], 1);
    }
}

// ---------------- K2: deg -> norm = 1/max(deg,1) in place ----------------
__global__ void norm_kernel(float* __restrict__ deg, int n) {
    int i = blockIdx.x * blockDim.x + threadIdx.x;
    if (i < n) deg[i] = 1.0f / fmaxf(deg[i], 1.0f);
}

// ---------------- K3: exclusive scan of cnt -> row_ptr, init cursor ----------------
// single block of 1024 threads; each thread owns a contiguous CHUNK of nodes.
__global__ __launch_bounds__(SCAN_T) void scan_kernel(const int* __restrict__ cnt,
                                                      int* __restrict__ row_ptr,
                                                      int* __restrict__ cursor) {
    __shared__ int lds[SCAN_T];
    const int t = threadIdx.x;
    const int lo = t * CHUNK;
    const int hi = min(lo + CHUNK, N_NODES);
    int s = 0;
    for (int i = lo; i < hi; ++i) s += cnt[i];
    lds[t] = s;
    __syncthreads();
    // Hillis-Steele inclusive scan over 1024 partials
    for (int off = 1; off < SCAN_T; off <<= 1) {
        int v = (t >= off) ? lds[t - off] : 0;
        __syncthreads();
        lds[t] += v;
        __syncthreads();
    }
    int base = (t == 0) ? 0 : lds[t - 1];
    for (int i = lo; i < hi; ++i) {
        row_ptr[i] = base;
        cursor[i]  = base;
        base += cnt[i];
    }
    if (t == SCAN_T - 1) row_ptr[N_NODES] = lds[SCAN_T - 1];  // == E
}

// ---------------- K4: bucketize edges into CSR slots ----------------
__global__ void bucket_kernel(const int* __restrict__ src, const int* __restrict__ dst,
                              const int* __restrict__ ef,
                              const float* __restrict__ edge_weight,
                              int* __restrict__ cursor,
                              int* __restrict__ slot_src, float* __restrict__ slot_w, int E) {
    int e = blockIdx.x * blockDim.x + threadIdx.x;
    if (e < E) {
        float w = edge_weight[ef[e] - 1] * ALPHA;
        float ew = w > 0.0f ? w : 0.01f * w;
        int slot = atomicAdd(&cursor[dst[e]], 1);
        slot_src[slot] = src[e];
        slot_w[slot]   = ew;
    }
}

// ---------------- K5: acc = feat @ weight; out = acc + bias; Hs = acc * norm ----------------
// 16 rows per block, 256 threads. weight [128][64] in LDS (32KB), feat rows (8KB).
__global__ __launch_bounds__(256) void gemm_kernel(
    const float* __restrict__ feat, const float* __restrict__ weight,
    const float* __restrict__ bias, const float* __restrict__ norm,
    float* __restrict__ Hs, float* __restrict__ out) {
    __shared__ float wS[IN_F][OUT_F];   // 32 KB
    __shared__ float fS[16][IN_F];      // 8 KB

    const int t = threadIdx.x;
    const int row0 = blockIdx.x * 16;

    for (int i = t; i < IN_F * OUT_F / 4; i += 256) {
        ((float4*)&wS[0][0])[i] = ((const float4*)weight)[i];
    }
    for (int i = t; i < 16 * IN_F / 4; i += 256) {
        int r = i >> 5;
        int c4 = i & 31;
        int n = row0 + r;
        float4 v = make_float4(0.f, 0.f, 0.f, 0.f);
        if (n < N_NODES) v = ((const float4*)feat)[n * (IN_F / 4) + c4];
        ((float4*)&fS[r][0])[c4] = v;
    }
    __syncthreads();

    const int o = t & 63;       // output column
    const int rg = t >> 6;      // rows rg, rg+4, rg+8, rg+12
    float acc0 = 0.f, acc1 = 0.f, acc2 = 0.f, acc3 = 0.f;
#pragma unroll
    for (int k = 0; k < IN_F; ++k) {
        float w = wS[k][o];
        acc0 += fS[rg][k] * w;
        acc1 += fS[rg + 4][k] * w;
        acc2 += fS[rg + 8][k] * w;
        acc3 += fS[rg + 12][k] * w;
    }
    float b = bias[o];
    float accs[4] = {acc0, acc1, acc2, acc3};
#pragma unroll
    for (int i = 0; i < 4; ++i) {
        int n = row0 + rg + i * 4;
        if (n < N_NODES) {
            float a = accs[i];
            Hs[n * OUT_F + o]  = a * norm[n];   // message source: (feat*norm)@W == (feat@W)*norm
            out[n * OUT_F + o] = a + b;         // feat_root + bias
        }
    }
}

// ---------------- K6: gather-sum per dst node (no atomics) ----------------
// 256 threads = 4 waves; each wave owns one dst node; lane = output column.
__global__ __launch_bounds__(256) void gather_kernel(
    const int* __restrict__ row_ptr, const int* __restrict__ slot_src,
    const float* __restrict__ slot_w, const float* __restrict__ Hs,
    float* __restrict__ out) {
    const int o = threadIdx.x & 63;
    const int d = blockIdx.x * 4 + (threadIdx.x >> 6);
    if (d >= N_NODES) return;
    const int start = row_ptr[d];
    const int end   = row_ptr[d + 1];
    float acc = 0.f;
    for (int j = start; j < end; ++j) {
        int s   = slot_src[j];          // wave-uniform broadcast load
        float w = slot_w[j];            // wave-uniform broadcast load
        acc += Hs[s * OUT_F + o] * w;   // coalesced 256B row read, L2-resident
    }
    out[d * OUT_F + o] += acc;          // each (d,o) owned by exactly one thread
}

extern "C" void kernel_launch(void* const* d_in, const int* in_sizes, int n_in,
                              void* d_out, int out_size, void* d_ws, size_t ws_size,
                              hipStream_t stream) {
    const float* feat        = (const float*)d_in[0];   // [N,128]
    const float* edge_weight = (const float*)d_in[1];   // [8,1]
    const float* weight      = (const float*)d_in[2];   // [128,64]
    const float* bias        = (const float*)d_in[3];   // [64]
    const int*   src         = (const int*)d_in[4];     // [E]
    const int*   dst         = (const int*)d_in[5];     // [E]
    const int*   e_feat      = (const int*)d_in[6];     // [E]
    float* out = (float*)d_out;

    // workspace layout (4-byte units from base):
    //   [0,        100000)  deg / norm (float)
    //   [100000,   200000)  cnt (int)
    //   [200000,   300001)  row_ptr (int, N+1)
    //   [300004,   400004)  cursor (int)
    //   [400004,  2000004)  slot_src (int, E)
    //   [2000004, 3600004)  slot_w (float, E)
    //   [3600004,10000004)  Hs (float, N*64)          total = 40.0 MB
    float* wsf = (float*)d_ws;
    int*   wsi = (int*)d_ws;
    float* deg      = wsf;
    int*   cnt      = wsi + 100000;
    int*   row_ptr  = wsi + 200000;
    int*   cursor   = wsi + 300004;
    int*   slot_src = wsi + 400004;
    float* slot_w   = wsf + 2000004;
    float* Hs       = wsf + 3600004;

    // zero deg + cnt in one contiguous memset (they are adjacent)
    hipMemsetAsync(deg, 0, 200000 * sizeof(float), stream);

    deg_hist_kernel<<<(N_EDGES + 255) / 256, 256, 0, stream>>>(dst, e_feat, edge_weight,
                                                               deg, cnt, N_EDGES);
    norm_kernel<<<(N_NODES + 255) / 256, 256, 0, stream>>>(deg, N_NODES);
    scan_kernel<<<1, SCAN_T, 0, stream>>>(cnt, row_ptr, cursor);
    bucket_kernel<<<(N_EDGES + 255) / 256, 256, 0, stream>>>(src, dst, e_feat, edge_weight,
                                                             cursor, slot_src, slot_w, N_EDGES);
    gemm_kernel<<<(N_NODES + 15) / 16, 256, 0, stream>>>(feat, weight, bias, deg, Hs, out);
    gather_kernel<<<(N_NODES + 3) / 4, 256, 0, stream>>>(row_ptr, slot_src, slot_w, Hs, out);
}

// Round 8
// 677.577 us; speedup vs baseline: 1.3459x; 1.3459x over previous
//
#include <hip/hip_runtime.h>

#define N_NODES 100000
#define N_EDGES 1600000
#define IN_F 128
#define OUT_F 64
#define ALPHA 10.0f
#define SCAN_B ((N_NODES + 255) / 256)   // 391 blocks of 256

// ---------------- K1: float degree + int histogram ----------------
__global__ void deg_hist_kernel(const int* __restrict__ dst, const int* __restrict__ ef,
                                const float* __restrict__ edge_weight,
                                float* __restrict__ deg, int* __restrict__ cnt, int E) {
    int e = blockIdx.x * blockDim.x + threadIdx.x;
    if (e < E) {
        float w = edge_weight[ef[e] - 1] * ALPHA;
        float ew = w > 0.0f ? w : 0.01f * w;   // leaky_relu, slope 0.01
        int d = dst[e];
        atomicAdd(&deg[d], ew);
        atomicAdd(&cnt[d], 1);
    }
}

// ---------------- K2: deg -> norm = 1/max(deg,1) in place ----------------
__global__ void norm_kernel(float* __restrict__ deg, int n) {
    int i = blockIdx.x * blockDim.x + threadIdx.x;
    if (i < n) deg[i] = 1.0f / fmaxf(deg[i], 1.0f);
}

// ---------------- K3a: per-block scan of cnt -> excl (per-node), bsum (per-block) ----
__global__ __launch_bounds__(256) void scan_block_kernel(const int* __restrict__ cnt,
                                                         int* __restrict__ excl,
                                                         int* __restrict__ bsum) {
    __shared__ int lds[256];
    const int t = threadIdx.x;
    const int i = blockIdx.x * 256 + t;
    int c = (i < N_NODES) ? cnt[i] : 0;
    lds[t] = c;
    __syncthreads();
    // Hillis-Steele inclusive scan over 256
    for (int off = 1; off < 256; off <<= 1) {
        int v = (t >= off) ? lds[t - off] : 0;
        __syncthreads();
        lds[t] += v;
        __syncthreads();
    }
    if (i < N_NODES) excl[i] = lds[t] - c;       // exclusive within block
    if (t == 255) bsum[blockIdx.x] = lds[255];   // block total
}

// ---------------- K3b: scan 391 block sums -> exclusive block offsets ----------------
__global__ __launch_bounds__(512) void scan_top_kernel(const int* __restrict__ bsum,
                                                       int* __restrict__ boff) {
    __shared__ int lds[512];
    const int t = threadIdx.x;
    int c = (t < SCAN_B) ? bsum[t] : 0;
    lds[t] = c;
    __syncthreads();
    for (int off = 1; off < 512; off <<= 1) {
        int v = (t >= off) ? lds[t - off] : 0;
        __syncthreads();
        lds[t] += v;
        __syncthreads();
    }
    if (t < SCAN_B) boff[t] = lds[t] - c;        // exclusive
}

// ---------------- K3c: row_ptr/cursor = boff[b] + excl[i]; row_ptr[N] = E ------------
__global__ __launch_bounds__(256) void scan_final_kernel(const int* __restrict__ excl,
                                                         const int* __restrict__ boff,
                                                         int* __restrict__ row_ptr,
                                                         int* __restrict__ cursor) {
    const int i = blockIdx.x * 256 + threadIdx.x;
    if (i < N_NODES) {
        int v = boff[blockIdx.x] + excl[i];
        row_ptr[i] = v;
        cursor[i]  = v;
    }
    if (i == 0) row_ptr[N_NODES] = N_EDGES;      // total edge count is fixed
}

// ---------------- K4: bucketize edges into CSR slots ----------------
__global__ void bucket_kernel(const int* __restrict__ src, const int* __restrict__ dst,
                              const int* __restrict__ ef,
                              const float* __restrict__ edge_weight,
                              int* __restrict__ cursor,
                              int* __restrict__ slot_src, float* __restrict__ slot_w, int E) {
    int e = blockIdx.x * blockDim.x + threadIdx.x;
    if (e < E) {
        float w = edge_weight[ef[e] - 1] * ALPHA;
        float ew = w > 0.0f ? w : 0.01f * w;
        int slot = atomicAdd(&cursor[dst[e]], 1);
        slot_src[slot] = src[e];
        slot_w[slot]   = ew;
    }
}

// ---------------- K5: acc = feat @ weight; out = acc + bias; Hs = acc * norm ----------
// 16 rows per block, 256 threads. weight [128][64] in LDS (32KB), feat rows (8KB).
__global__ __launch_bounds__(256) void gemm_kernel(
    const float* __restrict__ feat, const float* __restrict__ weight,
    const float* __restrict__ bias, const float* __restrict__ norm,
    float* __restrict__ Hs, float* __restrict__ out) {
    __shared__ float wS[IN_F][OUT_F];   // 32 KB
    __shared__ float fS[16][IN_F];      // 8 KB

    const int t = threadIdx.x;
    const int row0 = blockIdx.x * 16;

    for (int i = t; i < IN_F * OUT_F / 4; i += 256) {
        ((float4*)&wS[0][0])[i] = ((const float4*)weight)[i];
    }
    for (int i = t; i < 16 * IN_F / 4; i += 256) {
        int r = i >> 5;
        int c4 = i & 31;
        int n = row0 + r;
        float4 v = make_float4(0.f, 0.f, 0.f, 0.f);
        if (n < N_NODES) v = ((const float4*)feat)[n * (IN_F / 4) + c4];
        ((float4*)&fS[r][0])[c4] = v;
    }
    __syncthreads();

    const int o = t & 63;       // output column
    const int rg = t >> 6;      // rows rg, rg+4, rg+8, rg+12
    float acc0 = 0.f, acc1 = 0.f, acc2 = 0.f, acc3 = 0.f;
#pragma unroll
    for (int k = 0; k < IN_F; ++k) {
        float w = wS[k][o];
        acc0 += fS[rg][k] * w;
        acc1 += fS[rg + 4][k] * w;
        acc2 += fS[rg + 8][k] * w;
        acc3 += fS[rg + 12][k] * w;
    }
    float b = bias[o];
    float accs[4] = {acc0, acc1, acc2, acc3};
#pragma unroll
    for (int i = 0; i < 4; ++i) {
        int n = row0 + rg + i * 4;
        if (n < N_NODES) {
            float a = accs[i];
            Hs[n * OUT_F + o]  = a * norm[n];   // (feat*norm)@W == (feat@W)*norm
            out[n * OUT_F + o] = a + b;         // feat_root + bias
        }
    }
}

// ---------------- K6: gather-sum per dst node (no atomics) ----------------
// 256 threads = 4 waves; each wave owns one dst node; lane = output column.
__global__ __launch_bounds__(256) void gather_kernel(
    const int* __restrict__ row_ptr, const int* __restrict__ slot_src,
    const float* __restrict__ slot_w, const float* __restrict__ Hs,
    float* __restrict__ out) {
    const int o = threadIdx.x & 63;
    const int d = blockIdx.x * 4 + (threadIdx.x >> 6);
    if (d >= N_NODES) return;
    const int start = row_ptr[d];
    const int end   = row_ptr[d + 1];
    float acc = 0.f;
    for (int j = start; j < end; ++j) {
        int s   = slot_src[j];          // wave-uniform broadcast load
        float w = slot_w[j];            // wave-uniform broadcast load
        acc += Hs[s * OUT_F + o] * w;   // coalesced 256B row read, cache-resident
    }
    out[d * OUT_F + o] += acc;          // each (d,o) owned by exactly one thread
}

extern "C" void kernel_launch(void* const* d_in, const int* in_sizes, int n_in,
                              void* d_out, int out_size, void* d_ws, size_t ws_size,
                              hipStream_t stream) {
    const float* feat        = (const float*)d_in[0];   // [N,128]
    const float* edge_weight = (const float*)d_in[1];   // [8,1]
    const float* weight      = (const float*)d_in[2];   // [128,64]
    const float* bias        = (const float*)d_in[3];   // [64]
    const int*   src         = (const int*)d_in[4];     // [E]
    const int*   dst         = (const int*)d_in[5];     // [E]
    const int*   e_feat      = (const int*)d_in[6];     // [E]
    float* out = (float*)d_out;

    // workspace layout (4-byte units from base):
    //   [0,        100000)  deg / norm (float)
    //   [100000,   200000)  cnt (int)
    //   [200000,   300001)  row_ptr (int, N+1)
    //   [300004,   400004)  cursor (int)
    //   [400004,  2000004)  slot_src (int, E)
    //   [2000004, 3600004)  slot_w (float, E)
    //   [3600004,10000004)  Hs (float, N*64)
    //   [10000004,10100004) excl (int, N)
    //   [10100004,10100395) bsum (int, SCAN_B)
    //   [10100400,10100791) boff (int, SCAN_B)        total ~= 40.4 MB
    float* wsf = (float*)d_ws;
    int*   wsi = (int*)d_ws;
    float* deg      = wsf;
    int*   cnt      = wsi + 100000;
    int*   row_ptr  = wsi + 200000;
    int*   cursor   = wsi + 300004;
    int*   slot_src = wsi + 400004;
    float* slot_w   = wsf + 2000004;
    float* Hs       = wsf + 3600004;
    int*   excl     = wsi + 10000004;
    int*   bsum     = wsi + 10100004;
    int*   boff     = wsi + 10100400;

    // zero deg + cnt in one contiguous memset (they are adjacent)
    hipMemsetAsync(deg, 0, 200000 * sizeof(float), stream);

    deg_hist_kernel<<<(N_EDGES + 255) / 256, 256, 0, stream>>>(dst, e_feat, edge_weight,
                                                               deg, cnt, N_EDGES);
    norm_kernel<<<(N_NODES + 255) / 256, 256, 0, stream>>>(deg, N_NODES);
    scan_block_kernel<<<SCAN_B, 256, 0, stream>>>(cnt, excl, bsum);
    scan_top_kernel<<<1, 512, 0, stream>>>(bsum, boff);
    scan_final_kernel<<<SCAN_B, 256, 0, stream>>>(excl, boff, row_ptr, cursor);
    bucket_kernel<<<(N_EDGES + 255) / 256, 256, 0, stream>>>(src, dst, e_feat, edge_weight,
                                                             cursor, slot_src, slot_w, N_EDGES);
    gemm_kernel<<<(N_NODES + 15) / 16, 256, 0, stream>>>(feat, weight, bias, deg, Hs, out);
    gather_kernel<<<(N_NODES + 3) / 4, 256, 0, stream>>>(row_ptr, slot_src, slot_w, Hs, out);
}

// Round 12
// 507.276 us; speedup vs baseline: 1.7978x; 1.3357x over previous
//
#include <hip/hip_runtime.h>

#define N_NODES 100000
#define N_EDGES 1600000
#define IN_F 128
#define OUT_F 64
#define ALPHA 10.0f
#define SCAN_B ((N_NODES + 255) / 256)   // 391 blocks of 256

// ---------------- K1: int histogram of dst (cnt only) ----------------
__global__ void hist_kernel(const int* __restrict__ dst, int* __restrict__ cnt, int E) {
    int e = blockIdx.x * blockDim.x + threadIdx.x;
    if (e < E) atomicAdd(&cnt[dst[e]], 1);
}

// ---------------- K3a: per-block scan of cnt -> excl (per-node), bsum (per-block) ----
__global__ __launch_bounds__(256) void scan_block_kernel(const int* __restrict__ cnt,
                                                         int* __restrict__ excl,
                                                         int* __restrict__ bsum) {
    __shared__ int lds[256];
    const int t = threadIdx.x;
    const int i = blockIdx.x * 256 + t;
    int c = (i < N_NODES) ? cnt[i] : 0;
    lds[t] = c;
    __syncthreads();
    for (int off = 1; off < 256; off <<= 1) {
        int v = (t >= off) ? lds[t - off] : 0;
        __syncthreads();
        lds[t] += v;
        __syncthreads();
    }
    if (i < N_NODES) excl[i] = lds[t] - c;       // exclusive within block
    if (t == 255) bsum[blockIdx.x] = lds[255];   // block total
}

// ---------------- K3b: scan 391 block sums -> exclusive block offsets ----------------
__global__ __launch_bounds__(512) void scan_top_kernel(const int* __restrict__ bsum,
                                                       int* __restrict__ boff) {
    __shared__ int lds[512];
    const int t = threadIdx.x;
    int c = (t < SCAN_B) ? bsum[t] : 0;
    lds[t] = c;
    __syncthreads();
    for (int off = 1; off < 512; off <<= 1) {
        int v = (t >= off) ? lds[t - off] : 0;
        __syncthreads();
        lds[t] += v;
        __syncthreads();
    }
    if (t < SCAN_B) boff[t] = lds[t] - c;        // exclusive
}

// ---------------- K3c: row_ptr/cursor = boff[b] + excl[i]; row_ptr[N] = E ------------
__global__ __launch_bounds__(256) void scan_final_kernel(const int* __restrict__ excl,
                                                         const int* __restrict__ boff,
                                                         int* __restrict__ row_ptr,
                                                         int* __restrict__ cursor) {
    const int i = blockIdx.x * 256 + threadIdx.x;
    if (i < N_NODES) {
        int v = boff[blockIdx.x] + excl[i];
        row_ptr[i] = v;
        cursor[i]  = v;
    }
    if (i == 0) row_ptr[N_NODES] = N_EDGES;
}

// ---------------- K4: bucketize edges into CSR slots ----------------
__global__ void bucket_kernel(const int* __restrict__ src, const int* __restrict__ dst,
                              const int* __restrict__ ef,
                              const float* __restrict__ edge_weight,
                              int* __restrict__ cursor,
                              int* __restrict__ slot_src, float* __restrict__ slot_w, int E) {
    int e = blockIdx.x * blockDim.x + threadIdx.x;
    if (e < E) {
        float w = edge_weight[ef[e] - 1] * ALPHA;
        float ew = w > 0.0f ? w : 0.01f * w;     // leaky_relu, slope 0.01
        int slot = atomicAdd(&cursor[dst[e]], 1);
        slot_src[slot] = src[e];
        slot_w[slot]   = ew;
    }
}

// ---------------- K4b: deg from bucketed slot_w; norm = 1/max(deg,1) --------------
// deg[d] = sum slot_w[row_ptr[d]..row_ptr[d+1])  ==  segment_sum(ew, dst)  (reordered)
__global__ __launch_bounds__(256) void deg_norm_kernel(const int* __restrict__ row_ptr,
                                                       const float* __restrict__ slot_w,
                                                       float* __restrict__ norm) {
    const int i = blockIdx.x * 256 + threadIdx.x;
    if (i < N_NODES) {
        const int a = row_ptr[i];
        const int b = row_ptr[i + 1];
        float s = 0.f;
        for (int j = a; j < b; ++j) s += slot_w[j];
        norm[i] = 1.0f / fmaxf(s, 1.0f);
    }
}

// ---------------- K5: register-blocked GEMM: 64x64 tile, 4x4 outputs/thread ----------
// acc = feat @ weight; out = acc + bias; Hs = acc * norm.
// fS4 is XOR-swizzled (column kk ^ (row&7)) to break the stride-512B bank conflict
// on ds_read_b128 row reads (G4); compute reads are 16-lane broadcasts across
// 4 distinct rows -> disjoint bank quads, conflict-free.
__global__ __launch_bounds__(256) void gemm_kernel(
    const float* __restrict__ feat, const float* __restrict__ weight,
    const float* __restrict__ bias, const float* __restrict__ norm,
    float* __restrict__ Hs, float* __restrict__ out) {
    __shared__ float4 fS4[64][32];    // 32 KB: fS4[r][kk ^ (r&7)] = feat4[row0+r][kk]
    __shared__ float4 wS4[IN_F][16];  // 32 KB: wS4[k][c4] = weight4[k][c4]

    const int t = threadIdx.x;
    const int row0 = blockIdx.x * 64;
    const float4* feat4   = (const float4*)feat;
    const float4* weight4 = (const float4*)weight;

    // stage weight: 2048 float4, linear
    for (int i = t; i < IN_F * 16; i += 256) {
        ((float4*)&wS4[0][0])[i] = weight4[i];
    }
    // stage feat rows, swizzled columns; coalesced global (32 lanes x 16B per row)
    for (int i = t; i < 64 * 32; i += 256) {
        int r  = i >> 5;
        int kk = i & 31;
        int n = row0 + r;
        float4 v = make_float4(0.f, 0.f, 0.f, 0.f);
        if (n < N_NODES) v = feat4[n * 32 + kk];
        fS4[r][kk ^ (r & 7)] = v;
    }
    __syncthreads();

    const int rIdx = t >> 4;       // 0..15 -> rows rIdx, rIdx+16, rIdx+32, rIdx+48
    const int cIdx = t & 15;       // 0..15 -> cols 4*cIdx .. 4*cIdx+3
    const int rsw  = rIdx & 7;     // row swizzle key (16*i == 0 mod 8)

    float4 acc[4];
#pragma unroll
    for (int i = 0; i < 4; ++i) acc[i] = make_float4(0.f, 0.f, 0.f, 0.f);

#pragma unroll 4
    for (int kk = 0; kk < 32; ++kk) {
        float4 a[4], b[4];
#pragma unroll
        for (int i = 0; i < 4; ++i) a[i] = fS4[rIdx + 16 * i][kk ^ rsw];
#pragma unroll
        for (int j = 0; j < 4; ++j) b[j] = wS4[4 * kk + j][cIdx];
#pragma unroll
        for (int i = 0; i < 4; ++i) {
            acc[i].x += a[i].x * b[0].x + a[i].y * b[1].x + a[i].z * b[2].x + a[i].w * b[3].x;
            acc[i].y += a[i].x * b[0].y + a[i].y * b[1].y + a[i].z * b[2].y + a[i].w * b[3].y;
            acc[i].z += a[i].x * b[0].z + a[i].y * b[1].z + a[i].z * b[2].z + a[i].w * b[3].z;
            acc[i].w += a[i].x * b[0].w + a[i].y * b[1].w + a[i].z * b[2].w + a[i].w * b[3].w;
        }
    }

    const float4 bia = ((const float4*)bias)[cIdx];
    float4* Hs4  = (float4*)Hs;
    float4* out4 = (float4*)out;
#pragma unroll
    for (int i = 0; i < 4; ++i) {
        int n = row0 + rIdx + 16 * i;
        if (n < N_NODES) {
            float nrm = norm[n];
            float4 h = acc[i];
            Hs4[n * 16 + cIdx]  = make_float4(h.x * nrm, h.y * nrm, h.z * nrm, h.w * nrm);
            out4[n * 16 + cIdx] = make_float4(h.x + bia.x, h.y + bia.y,
                                              h.z + bia.z, h.w + bia.w);
        }
    }
}

// ---------------- K6: gather-sum per dst node (no atomics) ----------------
__global__ __launch_bounds__(256) void gather_kernel(
    const int* __restrict__ row_ptr, const int* __restrict__ slot_src,
    const float* __restrict__ slot_w, const float* __restrict__ Hs,
    float* __restrict__ out) {
    const int o = threadIdx.x & 63;
    const int d = blockIdx.x * 4 + (threadIdx.x >> 6);
    if (d >= N_NODES) return;
    const int start = row_ptr[d];
    const int end   = row_ptr[d + 1];
    float acc = 0.f;
    for (int j = start; j < end; ++j) {
        int s   = slot_src[j];          // wave-uniform broadcast load
        float w = slot_w[j];            // wave-uniform broadcast load
        acc += Hs[s * OUT_F + o] * w;   // coalesced 256B row read, cache-resident
    }
    out[d * OUT_F + o] += acc;
}

extern "C" void kernel_launch(void* const* d_in, const int* in_sizes, int n_in,
                              void* d_out, int out_size, void* d_ws, size_t ws_size,
                              hipStream_t stream) {
    const float* feat        = (const float*)d_in[0];   // [N,128]
    const float* edge_weight = (const float*)d_in[1];   // [8,1]
    const float* weight      = (const float*)d_in[2];   // [128,64]
    const float* bias        = (const float*)d_in[3];   // [64]
    const int*   src         = (const int*)d_in[4];     // [E]
    const int*   dst         = (const int*)d_in[5];     // [E]
    const int*   e_feat      = (const int*)d_in[6];     // [E]
    float* out = (float*)d_out;

    // workspace layout (4-byte units from base):
    //   [0,        100000)  norm (float)          (written by deg_norm_kernel)
    //   [100000,   200000)  cnt (int)             (memset to 0)
    //   [200000,   300001)  row_ptr (int, N+1)
    //   [300004,   400004)  cursor (int)
    //   [400004,  2000004)  slot_src (int, E)
    //   [2000004, 3600004)  slot_w (float, E)
    //   [3600004,10000004)  Hs (float, N*64)
    //   [10000004,10100004) excl (int, N)
    //   [10100004,10100395) bsum (int, SCAN_B)
    //   [10100400,10100791) boff (int, SCAN_B)
    float* wsf = (float*)d_ws;
    int*   wsi = (int*)d_ws;
    float* norm     = wsf;
    int*   cnt      = wsi + 100000;
    int*   row_ptr  = wsi + 200000;
    int*   cursor   = wsi + 300004;
    int*   slot_src = wsi + 400004;
    float* slot_w   = wsf + 2000004;
    float* Hs       = wsf + 3600004;
    int*   excl     = wsi + 10000004;
    int*   bsum     = wsi + 10100004;
    int*   boff     = wsi + 10100400;

    hipMemsetAsync(cnt, 0, 100000 * sizeof(int), stream);

    hist_kernel<<<(N_EDGES + 255) / 256, 256, 0, stream>>>(dst, cnt, N_EDGES);
    scan_block_kernel<<<SCAN_B, 256, 0, stream>>>(cnt, excl, bsum);
    scan_top_kernel<<<1, 512, 0, stream>>>(bsum, boff);
    scan_final_kernel<<<SCAN_B, 256, 0, stream>>>(excl, boff, row_ptr, cursor);
    bucket_kernel<<<(N_EDGES + 255) / 256, 256, 0, stream>>>(src, dst, e_feat, edge_weight,
                                                             cursor, slot_src, slot_w, N_EDGES);
    deg_norm_kernel<<<SCAN_B, 256, 0, stream>>>(row_ptr, slot_w, norm);
    gemm_kernel<<<(N_NODES + 63) / 64, 256, 0, stream>>>(feat, weight, bias, norm, Hs, out);
    gather_kernel<<<(N_NODES + 3) / 4, 256, 0, stream>>>(row_ptr, slot_src, slot_w, Hs, out);
}

// Round 13
// 475.610 us; speedup vs baseline: 1.9175x; 1.0666x over previous
//
#include <hip/hip_runtime.h>
#include <hip/hip_bf16.h>

#define N_NODES 100000
#define N_EDGES 1600000
#define IN_F 128
#define OUT_F 64
#define ALPHA 10.0f
#define SCAN_B ((N_NODES + 255) / 256)   // 391 blocks of 256

// ---------------- K1: int histogram of dst (cnt only) ----------------
__global__ void hist_kernel(const int* __restrict__ dst, int* __restrict__ cnt, int E) {
    int e = blockIdx.x * blockDim.x + threadIdx.x;
    if (e < E) atomicAdd(&cnt[dst[e]], 1);
}

// ---------------- K3a: per-block scan of cnt -> excl (per-node), bsum (per-block) ----
__global__ __launch_bounds__(256) void scan_block_kernel(const int* __restrict__ cnt,
                                                         int* __restrict__ excl,
                                                         int* __restrict__ bsum) {
    __shared__ int lds[256];
    const int t = threadIdx.x;
    const int i = blockIdx.x * 256 + t;
    int c = (i < N_NODES) ? cnt[i] : 0;
    lds[t] = c;
    __syncthreads();
    for (int off = 1; off < 256; off <<= 1) {
        int v = (t >= off) ? lds[t - off] : 0;
        __syncthreads();
        lds[t] += v;
        __syncthreads();
    }
    if (i < N_NODES) excl[i] = lds[t] - c;       // exclusive within block
    if (t == 255) bsum[blockIdx.x] = lds[255];   // block total
}

// ---------------- K3b: scan 391 block sums -> exclusive block offsets ----------------
__global__ __launch_bounds__(512) void scan_top_kernel(const int* __restrict__ bsum,
                                                       int* __restrict__ boff) {
    __shared__ int lds[512];
    const int t = threadIdx.x;
    int c = (t < SCAN_B) ? bsum[t] : 0;
    lds[t] = c;
    __syncthreads();
    for (int off = 1; off < 512; off <<= 1) {
        int v = (t >= off) ? lds[t - off] : 0;
        __syncthreads();
        lds[t] += v;
        __syncthreads();
    }
    if (t < SCAN_B) boff[t] = lds[t] - c;        // exclusive
}

// ---------------- K3c: row_ptr/cursor = boff[b] + excl[i]; row_ptr[N] = E ------------
__global__ __launch_bounds__(256) void scan_final_kernel(const int* __restrict__ excl,
                                                         const int* __restrict__ boff,
                                                         int* __restrict__ row_ptr,
                                                         int* __restrict__ cursor) {
    const int i = blockIdx.x * 256 + threadIdx.x;
    if (i < N_NODES) {
        int v = boff[blockIdx.x] + excl[i];
        row_ptr[i] = v;
        cursor[i]  = v;
    }
    if (i == 0) row_ptr[N_NODES] = N_EDGES;
}

// ---------------- K4: bucketize edges into CSR slots (packed int2: src, w) ----------
__global__ void bucket_kernel(const int* __restrict__ src, const int* __restrict__ dst,
                              const int* __restrict__ ef,
                              const float* __restrict__ edge_weight,
                              int* __restrict__ cursor,
                              int2* __restrict__ slot, int E) {
    int e = blockIdx.x * blockDim.x + threadIdx.x;
    if (e < E) {
        float w = edge_weight[ef[e] - 1] * ALPHA;
        float ew = w > 0.0f ? w : 0.01f * w;     // leaky_relu, slope 0.01
        int sidx = atomicAdd(&cursor[dst[e]], 1);
        slot[sidx] = make_int2(src[e], __float_as_int(ew));   // one 8B store
    }
}

// ---------------- K4b: deg from bucketed slot.w; norm = 1/max(deg,1) --------------
__global__ __launch_bounds__(256) void deg_norm_kernel(const int* __restrict__ row_ptr,
                                                       const int2* __restrict__ slot,
                                                       float* __restrict__ norm) {
    const int i = blockIdx.x * 256 + threadIdx.x;
    if (i < N_NODES) {
        const int a = row_ptr[i];
        const int b = row_ptr[i + 1];
        float s = 0.f;
        for (int j = a; j < b; ++j) s += __int_as_float(slot[j].y);
        norm[i] = 1.0f / fmaxf(s, 1.0f);
    }
}

// ---------------- K5: register-blocked GEMM: 64x64 tile, 4x4 outputs/thread ----------
// acc = feat @ weight; out = acc + bias (fp32); Hs = bf16(acc * norm).
__global__ __launch_bounds__(256) void gemm_kernel(
    const float* __restrict__ feat, const float* __restrict__ weight,
    const float* __restrict__ bias, const float* __restrict__ norm,
    __hip_bfloat16* __restrict__ Hsb, float* __restrict__ out) {
    __shared__ float4 fS4[64][32];    // 32 KB: fS4[r][kk ^ (r&7)] = feat4[row0+r][kk]
    __shared__ float4 wS4[IN_F][16];  // 32 KB

    const int t = threadIdx.x;
    const int row0 = blockIdx.x * 64;
    const float4* feat4   = (const float4*)feat;
    const float4* weight4 = (const float4*)weight;

    for (int i = t; i < IN_F * 16; i += 256) {
        ((float4*)&wS4[0][0])[i] = weight4[i];
    }
    for (int i = t; i < 64 * 32; i += 256) {
        int r  = i >> 5;
        int kk = i & 31;
        int n = row0 + r;
        float4 v = make_float4(0.f, 0.f, 0.f, 0.f);
        if (n < N_NODES) v = feat4[n * 32 + kk];
        fS4[r][kk ^ (r & 7)] = v;
    }
    __syncthreads();

    const int rIdx = t >> 4;       // rows rIdx, rIdx+16, rIdx+32, rIdx+48
    const int cIdx = t & 15;       // cols 4*cIdx .. 4*cIdx+3
    const int rsw  = rIdx & 7;

    float4 acc[4];
#pragma unroll
    for (int i = 0; i < 4; ++i) acc[i] = make_float4(0.f, 0.f, 0.f, 0.f);

#pragma unroll 4
    for (int kk = 0; kk < 32; ++kk) {
        float4 a[4], b[4];
#pragma unroll
        for (int i = 0; i < 4; ++i) a[i] = fS4[rIdx + 16 * i][kk ^ rsw];
#pragma unroll
        for (int j = 0; j < 4; ++j) b[j] = wS4[4 * kk + j][cIdx];
#pragma unroll
        for (int i = 0; i < 4; ++i) {
            acc[i].x += a[i].x * b[0].x + a[i].y * b[1].x + a[i].z * b[2].x + a[i].w * b[3].x;
            acc[i].y += a[i].x * b[0].y + a[i].y * b[1].y + a[i].z * b[2].y + a[i].w * b[3].y;
            acc[i].z += a[i].x * b[0].z + a[i].y * b[1].z + a[i].z * b[2].z + a[i].w * b[3].z;
            acc[i].w += a[i].x * b[0].w + a[i].y * b[1].w + a[i].z * b[2].w + a[i].w * b[3].w;
        }
    }

    const float4 bia = ((const float4*)bias)[cIdx];
    float4* out4 = (float4*)out;
#pragma unroll
    for (int i = 0; i < 4; ++i) {
        int n = row0 + rIdx + 16 * i;
        if (n < N_NODES) {
            float nrm = norm[n];
            float4 h = acc[i];
            // Hs (bf16, 8B aligned vector store)
            __hip_bfloat16 b0 = __float2bfloat16(h.x * nrm);
            __hip_bfloat16 b1 = __float2bfloat16(h.y * nrm);
            __hip_bfloat16 b2 = __float2bfloat16(h.z * nrm);
            __hip_bfloat16 b3 = __float2bfloat16(h.w * nrm);
            ushort4 u = make_ushort4(*(unsigned short*)&b0, *(unsigned short*)&b1,
                                     *(unsigned short*)&b2, *(unsigned short*)&b3);
            *((ushort4*)(Hsb + n * OUT_F + 4 * cIdx)) = u;
            out4[n * 16 + cIdx] = make_float4(h.x + bia.x, h.y + bia.y,
                                              h.z + bia.z, h.w + bia.w);
        }
    }
}

// ---------------- K6: gather-sum per dst node (bf16 Hs, packed slots) --------------
__global__ __launch_bounds__(256) void gather_kernel(
    const int* __restrict__ row_ptr, const int2* __restrict__ slot,
    const __hip_bfloat16* __restrict__ Hsb, float* __restrict__ out) {
    const int o = threadIdx.x & 63;
    const int d = blockIdx.x * 4 + (threadIdx.x >> 6);
    if (d >= N_NODES) return;
    const int start = row_ptr[d];
    const int end   = row_ptr[d + 1];
    float acc = 0.f;
    for (int j = start; j < end; ++j) {
        int2 v  = slot[j];                       // wave-uniform 8B broadcast
        int s   = v.x;
        float w = __int_as_float(v.y);
        acc += __bfloat162float(Hsb[s * OUT_F + o]) * w;  // coalesced 128B row read
    }
    out[d * OUT_F + o] += acc;
}

extern "C" void kernel_launch(void* const* d_in, const int* in_sizes, int n_in,
                              void* d_out, int out_size, void* d_ws, size_t ws_size,
                              hipStream_t stream) {
    const float* feat        = (const float*)d_in[0];   // [N,128]
    const float* edge_weight = (const float*)d_in[1];   // [8,1]
    const float* weight      = (const float*)d_in[2];   // [128,64]
    const float* bias        = (const float*)d_in[3];   // [64]
    const int*   src         = (const int*)d_in[4];     // [E]
    const int*   dst         = (const int*)d_in[5];     // [E]
    const int*   e_feat      = (const int*)d_in[6];     // [E]
    float* out = (float*)d_out;

    // workspace layout (4-byte units from base):
    //   [0,        100000)  norm (float)
    //   [100000,   200000)  cnt (int)             (memset to 0)
    //   [200000,   300001)  row_ptr (int, N+1)
    //   [300004,   400004)  cursor (int)
    //   [400004,  3600004)  slot (int2, E)        8B-aligned (400004*4 % 8 == 0)
    //   [3600004,  6800004) Hs (bf16, N*64 = 12.8 MB)
    //   [6800004,  6900004) excl (int, N)
    //   [6900004,  6900395) bsum (int, SCAN_B)
    //   [6900400,  6900791) boff (int, SCAN_B)
    float* wsf = (float*)d_ws;
    int*   wsi = (int*)d_ws;
    float* norm     = wsf;
    int*   cnt      = wsi + 100000;
    int*   row_ptr  = wsi + 200000;
    int*   cursor   = wsi + 300004;
    int2*  slot     = (int2*)(wsi + 400004);
    __hip_bfloat16* Hsb = (__hip_bfloat16*)(wsi + 3600004);
    int*   excl     = wsi + 6800004;
    int*   bsum     = wsi + 6900004;
    int*   boff     = wsi + 6900400;

    hipMemsetAsync(cnt, 0, 100000 * sizeof(int), stream);

    hist_kernel<<<(N_EDGES + 255) / 256, 256, 0, stream>>>(dst, cnt, N_EDGES);
    scan_block_kernel<<<SCAN_B, 256, 0, stream>>>(cnt, excl, bsum);
    scan_top_kernel<<<1, 512, 0, stream>>>(bsum, boff);
    scan_final_kernel<<<SCAN_B, 256, 0, stream>>>(excl, boff, row_ptr, cursor);
    bucket_kernel<<<(N_EDGES + 255) / 256, 256, 0, stream>>>(src, dst, e_feat, edge_weight,
                                                             cursor, slot, N_EDGES);
    deg_norm_kernel<<<SCAN_B, 256, 0, stream>>>(row_ptr, slot, norm);
    gemm_kernel<<<(N_NODES + 63) / 64, 256, 0, stream>>>(feat, weight, bias, norm, Hsb, out);
    gather_kernel<<<(N_NODES + 3) / 4, 256, 0, stream>>>(row_ptr, slot, Hsb, out);
}

// Round 16
// 423.337 us; speedup vs baseline: 2.1542x; 1.1235x over previous
//
#include <hip/hip_runtime.h>
#include <hip/hip_bf16.h>

#define N_NODES 100000
#define N_EDGES 1600000
#define IN_F 128
#define OUT_F 64
#define ALPHA 10.0f
#define SCAN_B ((N_NODES + 255) / 256)   // 391 blocks of 256

// ---------------- K1: int histogram of dst (cnt only) ----------------
__global__ void hist_kernel(const int* __restrict__ dst, int* __restrict__ cnt, int E) {
    int e = blockIdx.x * blockDim.x + threadIdx.x;
    if (e < E) atomicAdd(&cnt[dst[e]], 1);
}

// ---------------- K3a: per-block scan of cnt -> excl (per-node), bsum (per-block) ----
__global__ __launch_bounds__(256) void scan_block_kernel(const int* __restrict__ cnt,
                                                         int* __restrict__ excl,
                                                         int* __restrict__ bsum) {
    __shared__ int lds[256];
    const int t = threadIdx.x;
    const int i = blockIdx.x * 256 + t;
    int c = (i < N_NODES) ? cnt[i] : 0;
    lds[t] = c;
    __syncthreads();
    for (int off = 1; off < 256; off <<= 1) {
        int v = (t >= off) ? lds[t - off] : 0;
        __syncthreads();
        lds[t] += v;
        __syncthreads();
    }
    if (i < N_NODES) excl[i] = lds[t] - c;       // exclusive within block
    if (t == 255) bsum[blockIdx.x] = lds[255];   // block total
}

// ---------------- K3b: scan 391 block sums -> exclusive block offsets ----------------
__global__ __launch_bounds__(512) void scan_top_kernel(const int* __restrict__ bsum,
                                                       int* __restrict__ boff) {
    __shared__ int lds[512];
    const int t = threadIdx.x;
    int c = (t < SCAN_B) ? bsum[t] : 0;
    lds[t] = c;
    __syncthreads();
    for (int off = 1; off < 512; off <<= 1) {
        int v = (t >= off) ? lds[t - off] : 0;
        __syncthreads();
        lds[t] += v;
        __syncthreads();
    }
    if (t < SCAN_B) boff[t] = lds[t] - c;        // exclusive
}

// ---------------- K3c: row_ptr/cursor = boff[b] + excl[i]; row_ptr[N] = E ------------
__global__ __launch_bounds__(256) void scan_final_kernel(const int* __restrict__ excl,
                                                         const int* __restrict__ boff,
                                                         int* __restrict__ row_ptr,
                                                         int* __restrict__ cursor) {
    const int i = blockIdx.x * 256 + threadIdx.x;
    if (i < N_NODES) {
        int v = boff[blockIdx.x] + excl[i];
        row_ptr[i] = v;
        cursor[i]  = v;
    }
    if (i == 0) row_ptr[N_NODES] = N_EDGES;
}

// ---------------- K4: bucketize edges into CSR slots (packed int2: src, w) ----------
__global__ void bucket_kernel(const int* __restrict__ src, const int* __restrict__ dst,
                              const int* __restrict__ ef,
                              const float* __restrict__ edge_weight,
                              int* __restrict__ cursor,
                              int2* __restrict__ slot, int E) {
    int e = blockIdx.x * blockDim.x + threadIdx.x;
    if (e < E) {
        float w = edge_weight[ef[e] - 1] * ALPHA;
        float ew = w > 0.0f ? w : 0.01f * w;     // leaky_relu, slope 0.01
        int sidx = atomicAdd(&cursor[dst[e]], 1);
        slot[sidx] = make_int2(src[e], __float_as_int(ew));   // one 8B store
    }
}

// ---------------- K4b: deg from bucketed slot.w; norm = 1/max(deg,1) --------------
__global__ __launch_bounds__(256) void deg_norm_kernel(const int* __restrict__ row_ptr,
                                                       const int2* __restrict__ slot,
                                                       float* __restrict__ norm) {
    const int i = blockIdx.x * 256 + threadIdx.x;
    if (i < N_NODES) {
        const int a = row_ptr[i];
        const int b = row_ptr[i + 1];
        float s = 0.f;
        for (int j = a; j < b; ++j) s += __int_as_float(slot[j].y);
        norm[i] = 1.0f / fmaxf(s, 1.0f);
    }
}

// ---------------- K5: register-blocked GEMM: 64x64 tile, 4x4 outputs/thread ----------
// acc = feat @ weight; out = acc + bias (fp32); Hs = bf16(acc * norm).
__global__ __launch_bounds__(256) void gemm_kernel(
    const float* __restrict__ feat, const float* __restrict__ weight,
    const float* __restrict__ bias, const float* __restrict__ norm,
    __hip_bfloat16* __restrict__ Hsb, float* __restrict__ out) {
    __shared__ float4 fS4[64][32];    // 32 KB: fS4[r][kk ^ (r&7)] = feat4[row0+r][kk]
    __shared__ float4 wS4[IN_F][16];  // 32 KB

    const int t = threadIdx.x;
    const int row0 = blockIdx.x * 64;
    const float4* feat4   = (const float4*)feat;
    const float4* weight4 = (const float4*)weight;

    for (int i = t; i < IN_F * 16; i += 256) {
        ((float4*)&wS4[0][0])[i] = weight4[i];
    }
    for (int i = t; i < 64 * 32; i += 256) {
        int r  = i >> 5;
        int kk = i & 31;
        int n = row0 + r;
        float4 v = make_float4(0.f, 0.f, 0.f, 0.f);
        if (n < N_NODES) v = feat4[n * 32 + kk];
        fS4[r][kk ^ (r & 7)] = v;
    }
    __syncthreads();

    const int rIdx = t >> 4;       // rows rIdx, rIdx+16, rIdx+32, rIdx+48
    const int cIdx = t & 15;       // cols 4*cIdx .. 4*cIdx+3
    const int rsw  = rIdx & 7;

    float4 acc[4];
#pragma unroll
    for (int i = 0; i < 4; ++i) acc[i] = make_float4(0.f, 0.f, 0.f, 0.f);

#pragma unroll 4
    for (int kk = 0; kk < 32; ++kk) {
        float4 a[4], b[4];
#pragma unroll
        for (int i = 0; i < 4; ++i) a[i] = fS4[rIdx + 16 * i][kk ^ rsw];
#pragma unroll
        for (int j = 0; j < 4; ++j) b[j] = wS4[4 * kk + j][cIdx];
#pragma unroll
        for (int i = 0; i < 4; ++i) {
            acc[i].x += a[i].x * b[0].x + a[i].y * b[1].x + a[i].z * b[2].x + a[i].w * b[3].x;
            acc[i].y += a[i].x * b[0].y + a[i].y * b[1].y + a[i].z * b[2].y + a[i].w * b[3].y;
            acc[i].z += a[i].x * b[0].z + a[i].y * b[1].z + a[i].z * b[2].z + a[i].w * b[3].z;
            acc[i].w += a[i].x * b[0].w + a[i].y * b[1].w + a[i].z * b[2].w + a[i].w * b[3].w;
        }
    }

    const float4 bia = ((const float4*)bias)[cIdx];
    float4* out4 = (float4*)out;
#pragma unroll
    for (int i = 0; i < 4; ++i) {
        int n = row0 + rIdx + 16 * i;
        if (n < N_NODES) {
            float nrm = norm[n];
            float4 h = acc[i];
            __hip_bfloat16 b0 = __float2bfloat16(h.x * nrm);
            __hip_bfloat16 b1 = __float2bfloat16(h.y * nrm);
            __hip_bfloat16 b2 = __float2bfloat16(h.z * nrm);
            __hip_bfloat16 b3 = __float2bfloat16(h.w * nrm);
            ushort4 u = make_ushort4(*(unsigned short*)&b0, *(unsigned short*)&b1,
                                     *(unsigned short*)&b2, *(unsigned short*)&b3);
            *((ushort4*)(Hsb + n * OUT_F + 4 * cIdx)) = u;
            out4[n * 16 + cIdx] = make_float4(h.x + bia.x, h.y + bia.y,
                                              h.z + bia.z, h.w + bia.w);
        }
    }
}

// ---------------- K6: gather-sum per dst node — 8-way predicated unroll --------------
// R13 diagnosis: latency-bound, MLP=1 (dependent slot->Hs chain, no unroll on runtime
// trip count). Fix: 8 predicated loads per outer iter (clamped index, zeroed weight)
// so 8 independent Hs row loads are in flight per wave. No divergent tail.
__global__ __launch_bounds__(256) void gather_kernel(
    const int* __restrict__ row_ptr, const int2* __restrict__ slot,
    const __hip_bfloat16* __restrict__ Hsb, float* __restrict__ out) {
    const int o = threadIdx.x & 63;
    const int d = blockIdx.x * 4 + (threadIdx.x >> 6);
    if (d >= N_NODES) return;
    const int start = row_ptr[d];
    const int end   = row_ptr[d + 1];
    float acc = 0.f;
    for (int j = start; j < end; j += 8) {
        int   s[8];
        float w[8];
#pragma unroll
        for (int u = 0; u < 8; ++u) {
            int jj = j + u;
            int jc = min(jj, end - 1);           // clamped: always a valid slot
            int2 v = slot[jc];                   // wave-uniform 8B broadcast
            s[u] = v.x;
            w[u] = (jj < end) ? __int_as_float(v.y) : 0.f;   // mask via weight
        }
        float h[8];
#pragma unroll
        for (int u = 0; u < 8; ++u) {
            h[u] = __bfloat162float(Hsb[s[u] * OUT_F + o]);  // 8 independent row loads
        }
#pragma unroll
        for (int u = 0; u < 8; ++u) acc += h[u] * w[u];
    }
    out[d * OUT_F + o] += acc;
}

extern "C" void kernel_launch(void* const* d_in, const int* in_sizes, int n_in,
                              void* d_out, int out_size, void* d_ws, size_t ws_size,
                              hipStream_t stream) {
    const float* feat        = (const float*)d_in[0];   // [N,128]
    const float* edge_weight = (const float*)d_in[1];   // [8,1]
    const float* weight      = (const float*)d_in[2];   // [128,64]
    const float* bias        = (const float*)d_in[3];   // [64]
    const int*   src         = (const int*)d_in[4];     // [E]
    const int*   dst         = (const int*)d_in[5];     // [E]
    const int*   e_feat      = (const int*)d_in[6];     // [E]
    float* out = (float*)d_out;

    // workspace layout (4-byte units from base):
    //   [0,        100000)  norm (float)
    //   [100000,   200000)  cnt (int)             (memset to 0)
    //   [200000,   300001)  row_ptr (int, N+1)
    //   [300004,   400004)  cursor (int)
    //   [400004,  3600004)  slot (int2, E)        8B-aligned
    //   [3600004,  6800004) Hs (bf16, N*64 = 12.8 MB)
    //   [6800004,  6900004) excl (int, N)
    //   [6900004,  6900395) bsum (int, SCAN_B)
    //   [6900400,  6900791) boff (int, SCAN_B)
    float* wsf = (float*)d_ws;
    int*   wsi = (int*)d_ws;
    float* norm     = wsf;
    int*   cnt      = wsi + 100000;
    int*   row_ptr  = wsi + 200000;
    int*   cursor   = wsi + 300004;
    int2*  slot     = (int2*)(wsi + 400004);
    __hip_bfloat16* Hsb = (__hip_bfloat16*)(wsi + 3600004);
    int*   excl     = wsi + 6800004;
    int*   bsum     = wsi + 6900004;
    int*   boff     = wsi + 6900400;

    hipMemsetAsync(cnt, 0, 100000 * sizeof(int), stream);

    hist_kernel<<<(N_EDGES + 255) / 256, 256, 0, stream>>>(dst, cnt, N_EDGES);
    scan_block_kernel<<<SCAN_B, 256, 0, stream>>>(cnt, excl, bsum);
    scan_top_kernel<<<1, 512, 0, stream>>>(bsum, boff);
    scan_final_kernel<<<SCAN_B, 256, 0, stream>>>(excl, boff, row_ptr, cursor);
    bucket_kernel<<<(N_EDGES + 255) / 256, 256, 0, stream>>>(src, dst, e_feat, edge_weight,
                                                             cursor, slot, N_EDGES);
    deg_norm_kernel<<<SCAN_B, 256, 0, stream>>>(row_ptr, slot, norm);
    gemm_kernel<<<(N_NODES + 63) / 64, 256, 0, stream>>>(feat, weight, bias, norm, Hsb, out);
    gather_kernel<<<(N_NODES + 3) / 4, 256, 0, stream>>>(row_ptr, slot, Hsb, out);
}